// Round 1
// baseline (1177.591 us; speedup 1.0000x reference)
//
#include <hip/hip_runtime.h>
#include <hip/hip_bf16.h>

#define BATCH   16384
#define IN_F    1024
#define OUT_F   1024
#define KCOLS   11
#define KPL     12          // 11 basis planes + 1 x-plane (for W)
#define KP      (KPL*IN_F)  // 12288
#define LN_EPS  1e-5f

typedef __attribute__((ext_vector_type(8))) short short8;
typedef __attribute__((ext_vector_type(4))) float f32x4;

static __device__ __forceinline__ unsigned short f2bf(float f) {
  __hip_bfloat16 h = __float2bfloat16(f);
  return *reinterpret_cast<unsigned short*>(&h);
}

// Cox-de Boor, faithful to the reference's in-place variant.
// knots[j] = j * fp32(1/11)  (matches jnp.linspace fp32), knots[11] = 1.0f.
__device__ __forceinline__ void bspline_basis(float x, float bas[KCOLS]) {
  const float s = 1.0f / 11.0f;
  float kn[12];
#pragma unroll
  for (int j = 0; j < 12; ++j) kn[j] = (float)j * s;
  kn[11] = 1.0f;
#pragma unroll
  for (int j = 0; j < 11; ++j)
    bas[j] = (x >= kn[j] && x < kn[j + 1]) ? 1.0f : 0.0f;
#pragma unroll
  for (int d = 1; d <= 3; ++d) {
#pragma unroll
    for (int j = 0; j < 11 - d; ++j) {
      float a = (x - kn[j]) / (kn[j + d] - kn[j]);
      float c = (kn[j + d + 1] - x) / (kn[j + d + 1] - kn[j + 1]);
      bas[j] = a * bas[j] + c * bas[j + 1];
    }
  }
}

// A[localRow][k*1024 + i] (bf16): 11 basis planes + x plane.
__global__ __launch_bounds__(256) void featgen(const float* __restrict__ X,
                                               unsigned short* __restrict__ A,
                                               int row0) {
  const int brow = blockIdx.x;
  const int i0 = threadIdx.x * 4;
  const float4 xv = *reinterpret_cast<const float4*>(X + (size_t)(row0 + brow) * IN_F + i0);
  float xs[4] = {xv.x, xv.y, xv.z, xv.w};
  float bas[4][KCOLS];
#pragma unroll
  for (int t = 0; t < 4; ++t) bspline_basis(xs[t], bas[t]);
  unsigned short* outp = A + (size_t)brow * KP + i0;
#pragma unroll
  for (int k = 0; k < KCOLS; ++k) {
    ushort4 u;
    u.x = f2bf(bas[0][k]); u.y = f2bf(bas[1][k]);
    u.z = f2bf(bas[2][k]); u.w = f2bf(bas[3][k]);
    *reinterpret_cast<ushort4*>(outp + (size_t)k * IN_F) = u;
  }
  ushort4 u;
  u.x = f2bf(xs[0]); u.y = f2bf(xs[1]); u.z = f2bf(xs[2]); u.w = f2bf(xs[3]);
  *reinterpret_cast<ushort4*>(outp + (size_t)KCOLS * IN_F) = u;
}

// Bmat[o][k*1024 + i] (bf16): cp planes + W plane.  (N-major weight matrix)
__global__ __launch_bounds__(256) void bgen(const float* __restrict__ CP,
                                            const float* __restrict__ W,
                                            unsigned short* __restrict__ Bm) {
  const int o = blockIdx.x;
  const int i0 = threadIdx.x * 4;
  unsigned short* outp = Bm + (size_t)o * KP + i0;
#pragma unroll
  for (int k = 0; k < KCOLS; ++k) {
    ushort4 u;
    u.x = f2bf(CP[((size_t)o * IN_F + i0 + 0) * KCOLS + k]);
    u.y = f2bf(CP[((size_t)o * IN_F + i0 + 1) * KCOLS + k]);
    u.z = f2bf(CP[((size_t)o * IN_F + i0 + 2) * KCOLS + k]);
    u.w = f2bf(CP[((size_t)o * IN_F + i0 + 3) * KCOLS + k]);
    *reinterpret_cast<ushort4*>(outp + (size_t)k * IN_F) = u;
  }
  ushort4 u;
  u.x = f2bf(W[(size_t)o * IN_F + i0 + 0]);
  u.y = f2bf(W[(size_t)o * IN_F + i0 + 1]);
  u.z = f2bf(W[(size_t)o * IN_F + i0 + 2]);
  u.w = f2bf(W[(size_t)o * IN_F + i0 + 3]);
  *reinterpret_cast<ushort4*>(outp + (size_t)KCOLS * IN_F) = u;
}

// C[rows][1024] = A[rows][12288] * Bm[1024][12288]^T   (both K-major, bf16 -> fp32)
// m97 structure: 128x128 tile, BK=64, 4 waves (2x2 of 64x64), global_load_lds w16.
__global__ __launch_bounds__(256) void gemm_nt(const unsigned short* __restrict__ A,
                                               const unsigned short* __restrict__ Bm,
                                               float* __restrict__ C) {
  __shared__ __align__(128) unsigned short As[128 * 64];
  __shared__ __align__(128) unsigned short Bs[128 * 64];
  const int tid = threadIdx.x;
  const int lane = tid & 63;
  const int wave = tid >> 6;
  const int bn = blockIdx.x;   // 0..7
  const int bm = blockIdx.y;
  const int wr = wave >> 1, wc = wave & 1;

  f32x4 acc[4][4] = {};

  // staging: per wave 4 issues; issue t covers tile rows (wave*4+t)*8 + lane/8, cols (lane%8)*8..+7
  const int srow = lane >> 3;
  const int scol = (lane & 7) * 8;
  const unsigned short* aSrc = A + (size_t)(bm * 128 + wave * 32 + srow) * KP + scol;
  const unsigned short* bSrc = Bm + (size_t)(bn * 128 + wave * 32 + srow) * KP + scol;

  for (int kt = 0; kt < KP / 64; ++kt) {
    __syncthreads();
    const unsigned short* ga = aSrc + kt * 64;
    const unsigned short* gb = bSrc + kt * 64;
#pragma unroll
    for (int t = 0; t < 4; ++t) {
      __builtin_amdgcn_global_load_lds(
          (const __attribute__((address_space(1))) void*)(ga + (size_t)t * 8 * KP),
          (__attribute__((address_space(3))) void*)(As + (wave * 4 + t) * 512), 16, 0, 0);
      __builtin_amdgcn_global_load_lds(
          (const __attribute__((address_space(1))) void*)(gb + (size_t)t * 8 * KP),
          (__attribute__((address_space(3))) void*)(Bs + (wave * 4 + t) * 512), 16, 0, 0);
    }
    __syncthreads();   // compiler emits s_waitcnt vmcnt(0) before s_barrier

#pragma unroll
    for (int kk = 0; kk < 2; ++kk) {
      const int kcol = kk * 32 + (lane >> 4) * 8;
      short8 af[4], bfr[4];
#pragma unroll
      for (int m = 0; m < 4; ++m)
        af[m] = *reinterpret_cast<const short8*>(As + (wr * 64 + m * 16 + (lane & 15)) * 64 + kcol);
#pragma unroll
      for (int n = 0; n < 4; ++n)
        bfr[n] = *reinterpret_cast<const short8*>(Bs + (wc * 64 + n * 16 + (lane & 15)) * 64 + kcol);
#pragma unroll
      for (int m = 0; m < 4; ++m)
#pragma unroll
        for (int n = 0; n < 4; ++n)
          acc[m][n] = __builtin_amdgcn_mfma_f32_16x16x32_bf16(af[m], bfr[n], acc[m][n], 0, 0, 0);
    }
  }

  // C/D layout (verified m89/m91): col = lane&15, row = (lane>>4)*4 + reg
  const int r0 = bm * 128 + wr * 64;
  const int c0 = bn * 128 + wc * 64 + (lane & 15);
  const int rsub = (lane >> 4) * 4;
#pragma unroll
  for (int m = 0; m < 4; ++m)
#pragma unroll
    for (int n = 0; n < 4; ++n)
#pragma unroll
      for (int r = 0; r < 4; ++r)
        C[(size_t)(r0 + m * 16 + rsub + r) * OUT_F + (c0 + n * 16)] = acc[m][n][r];
}

// In-place row LayerNorm with bias add: out = gamma*(v-mu)*rsqrt(var+eps)+beta
__global__ __launch_bounds__(256) void ln_kernel(float* __restrict__ C,
                                                 const float* __restrict__ bias,
                                                 const float* __restrict__ gamma,
                                                 const float* __restrict__ beta) {
  const int row = blockIdx.x;
  const int tid = threadIdx.x;
  float4 v = *reinterpret_cast<const float4*>(C + (size_t)row * OUT_F + tid * 4);
  const float4 bb = *reinterpret_cast<const float4*>(bias + tid * 4);
  v.x += bb.x; v.y += bb.y; v.z += bb.z; v.w += bb.w;
  float s = v.x + v.y + v.z + v.w;
  float q = v.x * v.x + v.y * v.y + v.z * v.z + v.w * v.w;
#pragma unroll
  for (int off = 32; off > 0; off >>= 1) {
    s += __shfl_down(s, off);
    q += __shfl_down(q, off);
  }
  __shared__ float red[8];
  const int wave = tid >> 6, lane = tid & 63;
  if (lane == 0) { red[wave] = s; red[4 + wave] = q; }
  __syncthreads();
  s = red[0] + red[1] + red[2] + red[3];
  q = red[4] + red[5] + red[6] + red[7];
  const float mu = s * (1.0f / OUT_F);
  const float var = q * (1.0f / OUT_F) - mu * mu;
  const float rs = rsqrtf(var + LN_EPS);
  const float4 g = *reinterpret_cast<const float4*>(gamma + tid * 4);
  const float4 be = *reinterpret_cast<const float4*>(beta + tid * 4);
  float4 o;
  o.x = g.x * (v.x - mu) * rs + be.x;
  o.y = g.y * (v.y - mu) * rs + be.y;
  o.z = g.z * (v.z - mu) * rs + be.z;
  o.w = g.w * (v.w - mu) * rs + be.w;
  *reinterpret_cast<float4*>(C + (size_t)row * OUT_F + tid * 4) = o;
}

extern "C" void kernel_launch(void* const* d_in, const int* in_sizes, int n_in,
                              void* d_out, int out_size, void* d_ws, size_t ws_size,
                              hipStream_t stream) {
  const float* x     = (const float*)d_in[0];
  const float* cp    = (const float*)d_in[1];
  const float* W     = (const float*)d_in[2];
  const float* bias  = (const float*)d_in[3];
  const float* gamma = (const float*)d_in[4];
  const float* beta  = (const float*)d_in[5];
  float* out = (float*)d_out;

  unsigned short* Bm = (unsigned short*)d_ws;
  const size_t bBytes = (size_t)OUT_F * KP * sizeof(unsigned short);   // 24 MiB
  unsigned short* Afeat = (unsigned short*)((char*)d_ws + bBytes);
  size_t avail = ws_size > bBytes ? ws_size - bBytes : 0;
  long long chunkLL = (long long)(avail / ((size_t)KP * sizeof(unsigned short)));
  int chunk = (int)((chunkLL / 128) * 128);
  if (chunk > BATCH) chunk = BATCH;
  if (chunk < 128) chunk = 128;   // minimum footprint ~27 MiB of ws

  bgen<<<OUT_F, 256, 0, stream>>>(cp, W, Bm);
  for (int r0 = 0; r0 < BATCH; r0 += chunk) {
    const int rows = (BATCH - r0 < chunk) ? (BATCH - r0) : chunk;
    featgen<<<rows, 256, 0, stream>>>(x, Afeat, r0);
    gemm_nt<<<dim3(8, rows / 128), 256, 0, stream>>>(Afeat, Bm, out + (size_t)r0 * OUT_F);
  }
  ln_kernel<<<BATCH, 256, 0, stream>>>(out, bias, gamma, beta);
}

// Round 2
// 684.955 us; speedup vs baseline: 1.7192x; 1.7192x over previous
//
#include <hip/hip_runtime.h>
#include <hip/hip_bf16.h>

#define BATCH   16384
#define IN_F    1024
#define OUT_F   1024
#define KCOLS   11
#define KPL     12          // 11 basis planes + 1 x-plane (for W)
#define KP      (KPL*IN_F)  // 12288
#define NTK     (KP/64)     // 192 K-tiles of 64
#define NIT     (NTK/2)     // 96 main-loop iterations (2 K-tiles each)
#define LN_EPS  1e-5f

typedef __attribute__((ext_vector_type(8))) short short8;
typedef __attribute__((ext_vector_type(4))) float f32x4;

static __device__ __forceinline__ unsigned short f2bf(float f) {
  __hip_bfloat16 h = __float2bfloat16(f);
  return *reinterpret_cast<unsigned short*>(&h);
}

// Cox-de Boor, faithful to the reference's in-place variant.
// All denominators are compile-time constants -> multiply by folded reciprocal
// (1-2 ulp fp32 vs the reference's divide; invisible under bf16 rounding).
__device__ __forceinline__ void bspline_basis(float x, float bas[KCOLS]) {
  const float s = 1.0f / 11.0f;
  float kn[12];
#pragma unroll
  for (int j = 0; j < 12; ++j) kn[j] = (float)j * s;
  kn[11] = 1.0f;
#pragma unroll
  for (int j = 0; j < 11; ++j)
    bas[j] = (x >= kn[j] && x < kn[j + 1]) ? 1.0f : 0.0f;
#pragma unroll
  for (int d = 1; d <= 3; ++d) {
#pragma unroll
    for (int j = 0; j < 11 - d; ++j) {
      const float r1 = 1.0f / (kn[j + d] - kn[j]);          // constant-folded
      const float r2 = 1.0f / (kn[j + d + 1] - kn[j + 1]);  // constant-folded
      float a = (x - kn[j]) * r1;
      float c = (kn[j + d + 1] - x) * r2;
      bas[j] = a * bas[j] + c * bas[j + 1];
    }
  }
}

// A[localRow][k*1024 + i] (bf16): 11 basis planes + x plane.
__global__ __launch_bounds__(256) void featgen(const float* __restrict__ X,
                                               unsigned short* __restrict__ A,
                                               int row0) {
  const int brow = blockIdx.x;
  const int i0 = threadIdx.x * 4;
  const float4 xv = *reinterpret_cast<const float4*>(X + (size_t)(row0 + brow) * IN_F + i0);
  float xs[4] = {xv.x, xv.y, xv.z, xv.w};
  float bas[4][KCOLS];
#pragma unroll
  for (int t = 0; t < 4; ++t) bspline_basis(xs[t], bas[t]);
  unsigned short* outp = A + (size_t)brow * KP + i0;
#pragma unroll
  for (int k = 0; k < KCOLS; ++k) {
    ushort4 u;
    u.x = f2bf(bas[0][k]); u.y = f2bf(bas[1][k]);
    u.z = f2bf(bas[2][k]); u.w = f2bf(bas[3][k]);
    *reinterpret_cast<ushort4*>(outp + (size_t)k * IN_F) = u;
  }
  ushort4 u;
  u.x = f2bf(xs[0]); u.y = f2bf(xs[1]); u.z = f2bf(xs[2]); u.w = f2bf(xs[3]);
  *reinterpret_cast<ushort4*>(outp + (size_t)KCOLS * IN_F) = u;
}

// Bmat[o][k*1024 + i] (bf16): cp planes + W plane.  (N-major weight matrix)
__global__ __launch_bounds__(256) void bgen(const float* __restrict__ CP,
                                            const float* __restrict__ W,
                                            unsigned short* __restrict__ Bm) {
  const int o = blockIdx.x;
  const int i0 = threadIdx.x * 4;
  unsigned short* outp = Bm + (size_t)o * KP + i0;
#pragma unroll
  for (int k = 0; k < KCOLS; ++k) {
    ushort4 u;
    u.x = f2bf(CP[((size_t)o * IN_F + i0 + 0) * KCOLS + k]);
    u.y = f2bf(CP[((size_t)o * IN_F + i0 + 1) * KCOLS + k]);
    u.z = f2bf(CP[((size_t)o * IN_F + i0 + 2) * KCOLS + k]);
    u.w = f2bf(CP[((size_t)o * IN_F + i0 + 3) * KCOLS + k]);
    *reinterpret_cast<ushort4*>(outp + (size_t)k * IN_F) = u;
  }
  ushort4 u;
  u.x = f2bf(W[(size_t)o * IN_F + i0 + 0]);
  u.y = f2bf(W[(size_t)o * IN_F + i0 + 1]);
  u.z = f2bf(W[(size_t)o * IN_F + i0 + 2]);
  u.w = f2bf(W[(size_t)o * IN_F + i0 + 3]);
  *reinterpret_cast<ushort4*>(outp + (size_t)KCOLS * IN_F) = u;
}

// ---------------- 256x256 8-phase GEMM (m201-style, plain HIP) ----------------
// C[rows][1024] = A[rows][12288] * Bm[1024][12288]^T, bf16 -> fp32.
// 512 thr = 8 waves (2M x 4N); BK=64; LDS 128 KiB = 2 buf x {A,B} x 2 half x [128][64].
// XOR swizzle: byte ^= ((row&7)<<4), applied as inverse-swizzled global SOURCE
// (global_load_lds writes linearly) + swizzled ds_read offsets.

#define BAR()    __builtin_amdgcn_s_barrier()
#define SCHED0() __builtin_amdgcn_sched_barrier(0)
#define WAITV(N) asm volatile("s_waitcnt vmcnt(" #N ")" ::: "memory")

__global__ __launch_bounds__(512, 2) void gemm8p(const unsigned short* __restrict__ A,
                                                 const unsigned short* __restrict__ Bm,
                                                 float* __restrict__ C, int nbm) {
  __shared__ unsigned short lds[2][2][2][128 * 64];  // [buf][A=0/B=1][half][...]
  const int tid  = (int)threadIdx.x;
  const int lane = tid & 63;
  const int w    = tid >> 6;
  const int wm   = w >> 2;       // 0..1
  const int wn   = w & 3;        // 0..3

  // XCD-aware bijective swizzle (nwg % 8 == 0 guaranteed by launcher), bm-major
  // within an XCD so the 4 bn-blocks sharing an A panel land on one XCD L2.
  const int nwg = nbm * 4;
  const int cpx = nwg >> 3;
  const int bid = (int)blockIdx.x;
  const int swz = (bid & 7) * cpx + (bid >> 3);
  const int bm = swz >> 2, bn = swz & 3;

  // ---- staging geometry (per half-tile: 128 rows x 64 cols bf16 = 16 KiB,
  //      2 global_load_lds x 512 thr x 16 B). Linear LDS dest; source carries
  //      the inverse swizzle: col = 8*((lane&7)^(lane>>3)).
  const int srow = (w << 3) + (lane >> 3);            // 0..63 within one issue
  const int scol = ((lane & 7) ^ (lane >> 3)) << 3;   // element col, swizzled
  const unsigned short* aB = A  + (size_t)(bm * 256 + srow) * KP + scol;
  const unsigned short* bB = Bm + (size_t)(bn * 256 + srow) * KP + scol;

#define STAGE(T, AB, H, BUF)                                                          \
  do {                                                                                \
    if ((T) < NTK) {                                                                  \
      const unsigned short* g_ = ((AB) ? bB : aB) + (size_t)(H) * 128 * KP + (size_t)(T) * 64; \
      unsigned short* l_ = &lds[BUF][AB][H][w * 512];                                 \
      __builtin_amdgcn_global_load_lds((const __attribute__((address_space(1))) void*)g_,       \
                                       (__attribute__((address_space(3))) void*)l_, 16, 0, 0);  \
      __builtin_amdgcn_global_load_lds((const __attribute__((address_space(1))) void*)(g_ + (size_t)64 * KP), \
                                       (__attribute__((address_space(3))) void*)(l_ + 4096), 16, 0, 0); \
    }                                                                                 \
  } while (0)

  // ---- fragment-read geometry (ds_read_b128, swizzled col) ----
  const int fr = lane & 15;
  const int g4 = lane >> 4;
  const int s7 = lane & 7;
  const int col0 = ((g4 ^ s7) << 3);        // kk=0, elements
  const int col1 = (((4 + g4) ^ s7) << 3);  // kk=1
  const unsigned short* aH[2] = {&lds[0][0][wm][0], &lds[1][0][wm][0]};
  const unsigned short* bH[2] = {&lds[0][1][wn >> 1][0], &lds[1][1][wn >> 1][0]};
  const int brow0 = (wn & 1) * 64;

  short8 aF[4][2], bF0[2][2], bF1[2][2];
  f32x4 acc[8][4] = {};

#define LOADA(MB, BUF)                                                         \
  do {                                                                         \
    _Pragma("unroll") for (int m_ = 0; m_ < 4; ++m_) {                         \
      const unsigned short* p_ = aH[BUF] + ((MB) + m_) * 1024 + fr * 64;       \
      aF[m_][0] = *reinterpret_cast<const short8*>(p_ + col0);                 \
      aF[m_][1] = *reinterpret_cast<const short8*>(p_ + col1);                 \
    }                                                                          \
  } while (0)

#define LOADB(DST, NB, BUF)                                                    \
  do {                                                                         \
    _Pragma("unroll") for (int n_ = 0; n_ < 2; ++n_) {                         \
      const unsigned short* p_ = bH[BUF] + (brow0 + ((NB) + n_) * 16 + fr) * 64; \
      DST[n_][0] = *reinterpret_cast<const short8*>(p_ + col0);                \
      DST[n_][1] = *reinterpret_cast<const short8*>(p_ + col1);                \
    }                                                                          \
  } while (0)

#define MFMAQ(MB, NB, BF)                                                      \
  do {                                                                         \
    __builtin_amdgcn_s_setprio(1);                                             \
    _Pragma("unroll") for (int m_ = 0; m_ < 4; ++m_)                           \
    _Pragma("unroll") for (int n_ = 0; n_ < 2; ++n_)                           \
    _Pragma("unroll") for (int kk_ = 0; kk_ < 2; ++kk_)                        \
      acc[(MB) + m_][(NB) + n_] = __builtin_amdgcn_mfma_f32_16x16x32_bf16(     \
          aF[m_][kk_], BF[n_][kk_], acc[(MB) + m_][(NB) + n_], 0, 0, 0);       \
    __builtin_amdgcn_s_setprio(0);                                             \
  } while (0)

  // ---- prologue: tile0 (B0,B1,A0,A1) + tile1 (B0,B1); drain to 4 outstanding.
  STAGE(0, 1, 0, 0); STAGE(0, 1, 1, 0);
  STAGE(0, 0, 0, 0); STAGE(0, 0, 1, 0);
  STAGE(1, 1, 0, 1); STAGE(1, 1, 1, 1);
  WAITV(4);
  BAR();

#pragma unroll 1
  for (int j = 0; j < NIT; ++j) {
    const int tA = 2 * j + 1, tB2 = 2 * j + 2, tB3 = 2 * j + 3;
    // P1: quad(m0-3,n0-1) of tile 2j (buf0); stage A-half0 of tile 2j+1 -> buf1
    LOADA(0, 0); LOADB(bF0, 0, 0);
    STAGE(tA, 0, 0, 1);
    BAR();
    MFMAQ(0, 0, bF0);
    SCHED0(); BAR();
    // P2: quad(m0-3,n2-3); stage A-half1 of 2j+1
    LOADB(bF1, 2, 0);
    STAGE(tA, 0, 1, 1);
    BAR();
    MFMAQ(0, 2, bF1);
    SCHED0(); BAR();
    // P3: quad(m4-7,n0-1); stage B-half0 of 2j+2 -> buf0 (B reads of buf0 done @P2)
    LOADA(4, 0);
    STAGE(tB2, 1, 0, 0);
    BAR();
    MFMAQ(4, 0, bF0);
    SCHED0(); BAR();
    // P4: quad(m4-7,n2-3); stage B-half1 of 2j+2; counted vmcnt for buf1 tile
    STAGE(tB2, 1, 1, 0);
    BAR();
    MFMAQ(4, 2, bF1);
    if (j < NIT - 1) { WAITV(4); } else { WAITV(0); }
    SCHED0(); BAR();
    // P5: tile 2j+1 (buf1) quad(m0-3,n0-1); stage A-half0 of 2j+2 (A reads of buf0 done @P3)
    LOADA(0, 1); LOADB(bF0, 0, 1);
    STAGE(tB2, 0, 0, 0);
    BAR();
    MFMAQ(0, 0, bF0);
    SCHED0(); BAR();
    // P6: quad(m0-3,n2-3); stage A-half1 of 2j+2
    LOADB(bF1, 2, 1);
    STAGE(tB2, 0, 1, 0);
    BAR();
    MFMAQ(0, 2, bF1);
    SCHED0(); BAR();
    // P7: quad(m4-7,n0-1); stage B-half0 of 2j+3 -> buf1 (B reads of buf1 done @P6)
    LOADA(4, 1);
    STAGE(tB3, 1, 0, 1);
    BAR();
    MFMAQ(4, 0, bF0);
    SCHED0(); BAR();
    // P8: quad(m4-7,n2-3); stage B-half1 of 2j+3; counted vmcnt for next buf0 tile
    STAGE(tB3, 1, 1, 1);
    BAR();
    MFMAQ(4, 2, bF1);
    if (j < NIT - 1) { WAITV(4); }
    SCHED0(); BAR();
  }

  // C/D layout (verified m89/m91): col = lane&15, row = (lane>>4)*4 + reg
  const size_t r0 = (size_t)bm * 256 + wm * 128 + (lane >> 4) * 4;
  const int c0 = bn * 256 + wn * 64 + fr;
#pragma unroll
  for (int m = 0; m < 8; ++m)
#pragma unroll
    for (int n = 0; n < 4; ++n)
#pragma unroll
      for (int r = 0; r < 4; ++r)
        C[(r0 + m * 16 + r) * OUT_F + (c0 + n * 16)] = acc[m][n][r];
}

// In-place row LayerNorm with bias add: out = gamma*(v-mu)*rsqrt(var+eps)+beta
__global__ __launch_bounds__(256) void ln_kernel(float* __restrict__ C,
                                                 const float* __restrict__ bias,
                                                 const float* __restrict__ gamma,
                                                 const float* __restrict__ beta) {
  const int row = blockIdx.x;
  const int tid = threadIdx.x;
  float4 v = *reinterpret_cast<const float4*>(C + (size_t)row * OUT_F + tid * 4);
  const float4 bb = *reinterpret_cast<const float4*>(bias + tid * 4);
  v.x += bb.x; v.y += bb.y; v.z += bb.z; v.w += bb.w;
  float s = v.x + v.y + v.z + v.w;
  float q = v.x * v.x + v.y * v.y + v.z * v.z + v.w * v.w;
#pragma unroll
  for (int off = 32; off > 0; off >>= 1) {
    s += __shfl_down(s, off);
    q += __shfl_down(q, off);
  }
  __shared__ float red[8];
  const int wave = tid >> 6, lane = tid & 63;
  if (lane == 0) { red[wave] = s; red[4 + wave] = q; }
  __syncthreads();
  s = red[0] + red[1] + red[2] + red[3];
  q = red[4] + red[5] + red[6] + red[7];
  const float mu = s * (1.0f / OUT_F);
  const float var = q * (1.0f / OUT_F) - mu * mu;
  const float rs = rsqrtf(var + LN_EPS);
  const float4 g = *reinterpret_cast<const float4*>(gamma + tid * 4);
  const float4 be = *reinterpret_cast<const float4*>(beta + tid * 4);
  float4 o;
  o.x = g.x * (v.x - mu) * rs + be.x;
  o.y = g.y * (v.y - mu) * rs + be.y;
  o.z = g.z * (v.z - mu) * rs + be.z;
  o.w = g.w * (v.w - mu) * rs + be.w;
  *reinterpret_cast<float4*>(C + (size_t)row * OUT_F + tid * 4) = o;
}

extern "C" void kernel_launch(void* const* d_in, const int* in_sizes, int n_in,
                              void* d_out, int out_size, void* d_ws, size_t ws_size,
                              hipStream_t stream) {
  const float* x     = (const float*)d_in[0];
  const float* cp    = (const float*)d_in[1];
  const float* W     = (const float*)d_in[2];
  const float* bias  = (const float*)d_in[3];
  const float* gamma = (const float*)d_in[4];
  const float* beta  = (const float*)d_in[5];
  float* out = (float*)d_out;

  unsigned short* Bm = (unsigned short*)d_ws;
  const size_t bBytes = (size_t)OUT_F * KP * sizeof(unsigned short);   // 24 MiB
  unsigned short* Af = (unsigned short*)((char*)d_ws + bBytes);
  size_t avail = ws_size > bBytes ? ws_size - bBytes : 0;
  long long rowsFit = (long long)(avail / ((size_t)KP * sizeof(unsigned short)));
  int chunk = (int)((rowsFit / 512) * 512);   // keep nwg % 8 == 0
  if (chunk > BATCH) chunk = BATCH;
  if (chunk < 512) chunk = 512;

  bgen<<<OUT_F, 256, 0, stream>>>(cp, W, Bm);
  for (int r0 = 0; r0 < BATCH; r0 += chunk) {
    const int rows = (BATCH - r0 < chunk) ? (BATCH - r0) : chunk;
    featgen<<<rows, 256, 0, stream>>>(x, Af, r0);
    const int nbm = rows / 256;
    gemm8p<<<nbm * 4, 512, 0, stream>>>(Af, Bm, out + (size_t)r0 * OUT_F, nbm);
  }
  ln_kernel<<<BATCH, 256, 0, stream>>>(out, bias, gamma, beta);
}

// Round 3
// 676.699 us; speedup vs baseline: 1.7402x; 1.0122x over previous
//
#include <hip/hip_runtime.h>
#include <hip/hip_bf16.h>

#define BATCH   16384
#define IN_F    1024
#define OUT_F   1024
#define KCOLS   11
#define KPL     12          // 11 basis planes + 1 x-plane (for W)
#define KP      (KPL*IN_F)  // 12288
#define NTK     (KP/64)     // 192 K-tiles of 64
#define NIT     (NTK/2)     // 96 main-loop iterations (2 K-tiles each)
#define LN_EPS  1e-5f

typedef __attribute__((ext_vector_type(8))) short short8;
typedef __attribute__((ext_vector_type(4))) float f32x4;

static __device__ __forceinline__ unsigned short f2bf(float f) {
  __hip_bfloat16 h = __float2bfloat16(f);
  return *reinterpret_cast<unsigned short*>(&h);
}

// Cox-de Boor, faithful to the reference's in-place variant.
// All denominators are compile-time constants -> multiply by folded reciprocal.
__device__ __forceinline__ void bspline_basis(float x, float bas[KCOLS]) {
  const float s = 1.0f / 11.0f;
  float kn[12];
#pragma unroll
  for (int j = 0; j < 12; ++j) kn[j] = (float)j * s;
  kn[11] = 1.0f;
#pragma unroll
  for (int j = 0; j < 11; ++j)
    bas[j] = (x >= kn[j] && x < kn[j + 1]) ? 1.0f : 0.0f;
#pragma unroll
  for (int d = 1; d <= 3; ++d) {
#pragma unroll
    for (int j = 0; j < 11 - d; ++j) {
      const float r1 = 1.0f / (kn[j + d] - kn[j]);
      const float r2 = 1.0f / (kn[j + d + 1] - kn[j + 1]);
      float a = (x - kn[j]) * r1;
      float c = (kn[j + d + 1] - x) * r2;
      bas[j] = a * bas[j] + c * bas[j + 1];
    }
  }
}

// A[localRow][k*1024 + i] (bf16): 11 basis planes + x plane.
__global__ __launch_bounds__(256) void featgen(const float* __restrict__ X,
                                               unsigned short* __restrict__ A,
                                               int row0) {
  const int brow = blockIdx.x;
  const int i0 = threadIdx.x * 4;
  const float4 xv = *reinterpret_cast<const float4*>(X + (size_t)(row0 + brow) * IN_F + i0);
  float xs[4] = {xv.x, xv.y, xv.z, xv.w};
  float bas[4][KCOLS];
#pragma unroll
  for (int t = 0; t < 4; ++t) bspline_basis(xs[t], bas[t]);
  unsigned short* outp = A + (size_t)brow * KP + i0;
#pragma unroll
  for (int k = 0; k < KCOLS; ++k) {
    ushort4 u;
    u.x = f2bf(bas[0][k]); u.y = f2bf(bas[1][k]);
    u.z = f2bf(bas[2][k]); u.w = f2bf(bas[3][k]);
    *reinterpret_cast<ushort4*>(outp + (size_t)k * IN_F) = u;
  }
  ushort4 u;
  u.x = f2bf(xs[0]); u.y = f2bf(xs[1]); u.z = f2bf(xs[2]); u.w = f2bf(xs[3]);
  *reinterpret_cast<ushort4*>(outp + (size_t)KCOLS * IN_F) = u;
}

// Bmat[o][k*1024 + i] (bf16): cp planes + W plane.
__global__ __launch_bounds__(256) void bgen(const float* __restrict__ CP,
                                            const float* __restrict__ W,
                                            unsigned short* __restrict__ Bm) {
  const int o = blockIdx.x;
  const int i0 = threadIdx.x * 4;
  unsigned short* outp = Bm + (size_t)o * KP + i0;
#pragma unroll
  for (int k = 0; k < KCOLS; ++k) {
    ushort4 u;
    u.x = f2bf(CP[((size_t)o * IN_F + i0 + 0) * KCOLS + k]);
    u.y = f2bf(CP[((size_t)o * IN_F + i0 + 1) * KCOLS + k]);
    u.z = f2bf(CP[((size_t)o * IN_F + i0 + 2) * KCOLS + k]);
    u.w = f2bf(CP[((size_t)o * IN_F + i0 + 3) * KCOLS + k]);
    *reinterpret_cast<ushort4*>(outp + (size_t)k * IN_F) = u;
  }
  ushort4 u;
  u.x = f2bf(W[(size_t)o * IN_F + i0 + 0]);
  u.y = f2bf(W[(size_t)o * IN_F + i0 + 1]);
  u.z = f2bf(W[(size_t)o * IN_F + i0 + 2]);
  u.w = f2bf(W[(size_t)o * IN_F + i0 + 3]);
  *reinterpret_cast<ushort4*>(outp + (size_t)KCOLS * IN_F) = u;
}

// ---------------- 128x256 8-phase GEMM ----------------
// C[rows][1024] = A[rows][12288] * Bm[1024][12288]^T, bf16 -> fp32.
// 512 thr = 8 waves (2M x 4N); BK=64; LDS 96 KiB (A 2x16K, B 2x32K).
// Grid = (rows/128) x 4 -> 256 WGs at rows=8192 => exactly full CU fill.

#define BAR()    __builtin_amdgcn_s_barrier()
#define SCHED0() __builtin_amdgcn_sched_barrier(0)
#define WAITV(N) asm volatile("s_waitcnt vmcnt(" #N ")" ::: "memory")

__global__ __launch_bounds__(512, 2) void gemm8p(const unsigned short* __restrict__ A,
                                                 const unsigned short* __restrict__ Bm,
                                                 float* __restrict__ C, int nbm) {
  __shared__ unsigned short ldsA[2][128 * 64];   // 2 x 16 KiB
  __shared__ unsigned short ldsB[2][256 * 64];   // 2 x 32 KiB
  const int tid  = (int)threadIdx.x;
  const int lane = tid & 63;
  const int w    = tid >> 6;
  const int wm   = w >> 2;       // 0..1
  const int wn   = w & 3;        // 0..3

  // XCD-aware bijective swizzle (nwg % 8 == 0 guaranteed by launcher)
  const int nwg = nbm * 4;
  const int cpx = nwg >> 3;
  const int bid = (int)blockIdx.x;
  const int swz = (bid & 7) * cpx + (bid >> 3);
  const int bm = swz >> 2, bn = swz & 3;

  // staging: one issue = 512 thr x 16 B = 64 rows x 64 cols.
  // Linear LDS dest; source col carries the inverse swizzle c ^ (row&7).
  const int srow = (w << 3) + (lane >> 3);            // 0..63 within one issue
  const int scol = ((lane & 7) ^ (lane >> 3)) << 3;   // element col, swizzled
  const unsigned short* aB = A  + (size_t)(bm * 128 + srow) * KP + scol;
  const unsigned short* bB = Bm + (size_t)(bn * 256 + srow) * KP + scol;

// A tile: 2 issues (rows t*64). B tile: 4 issues.
#define STAGE_A(T, ISS, BUF)                                                          \
  do {                                                                                \
    if ((T) < NTK) {                                                                  \
      const unsigned short* g_ = aB + (size_t)(ISS) * 64 * KP + (size_t)(T) * 64;     \
      __builtin_amdgcn_global_load_lds((const __attribute__((address_space(1))) void*)g_, \
          (__attribute__((address_space(3))) void*)(&ldsA[BUF][(ISS) * 4096 + w * 512]), 16, 0, 0); \
    }                                                                                 \
  } while (0)

#define STAGE_B2(T, ISS, BUF)                                                         \
  do {                                                                                \
    if ((T) < NTK) {                                                                  \
      const unsigned short* g_ = bB + (size_t)(ISS) * 64 * KP + (size_t)(T) * 64;     \
      __builtin_amdgcn_global_load_lds((const __attribute__((address_space(1))) void*)g_, \
          (__attribute__((address_space(3))) void*)(&ldsB[BUF][(ISS) * 4096 + w * 512]), 16, 0, 0); \
      const unsigned short* g2_ = g_ + (size_t)64 * KP;                               \
      __builtin_amdgcn_global_load_lds((const __attribute__((address_space(1))) void*)g2_, \
          (__attribute__((address_space(3))) void*)(&ldsB[BUF][((ISS) + 1) * 4096 + w * 512]), 16, 0, 0); \
    }                                                                                 \
  } while (0)

  // fragment reads (ds_read_b128, swizzled col)
  const int fr = lane & 15;
  const int g4 = lane >> 4;
  const int s7 = lane & 7;
  const int col0 = ((g4 ^ s7) << 3);        // kk=0 (elements)
  const int col1 = (((4 + g4) ^ s7) << 3);  // kk=1

  short8 aF[2][2], bF0[2][2], bF1[2][2];
  f32x4 acc[4][4] = {};

#define LOADA(MB, BUF)                                                         \
  do {                                                                         \
    _Pragma("unroll") for (int m_ = 0; m_ < 2; ++m_) {                         \
      const unsigned short* p_ = &ldsA[BUF][(wm * 64 + ((MB) + m_) * 16 + fr) * 64]; \
      aF[m_][0] = *reinterpret_cast<const short8*>(p_ + col0);                 \
      aF[m_][1] = *reinterpret_cast<const short8*>(p_ + col1);                 \
    }                                                                          \
  } while (0)

#define LOADB(DST, NB, BUF)                                                    \
  do {                                                                         \
    _Pragma("unroll") for (int n_ = 0; n_ < 2; ++n_) {                         \
      const unsigned short* p_ = &ldsB[BUF][(wn * 64 + ((NB) + n_) * 16 + fr) * 64]; \
      DST[n_][0] = *reinterpret_cast<const short8*>(p_ + col0);                \
      DST[n_][1] = *reinterpret_cast<const short8*>(p_ + col1);                \
    }                                                                          \
  } while (0)

#define MFMAQ(MB, NB, BF)                                                      \
  do {                                                                         \
    __builtin_amdgcn_s_setprio(1);                                             \
    _Pragma("unroll") for (int m_ = 0; m_ < 2; ++m_)                           \
    _Pragma("unroll") for (int n_ = 0; n_ < 2; ++n_)                           \
    _Pragma("unroll") for (int kk_ = 0; kk_ < 2; ++kk_)                        \
      acc[(MB) + m_][(NB) + n_] = __builtin_amdgcn_mfma_f32_16x16x32_bf16(     \
          aF[m_][kk_], BF[n_][kk_], acc[(MB) + m_][(NB) + n_], 0, 0, 0);       \
    __builtin_amdgcn_s_setprio(0);                                             \
  } while (0)

  // prologue: tile0 -> buf0 (B 4 issues, A 2 issues); B of tile1 -> buf1.
  STAGE_B2(0, 0, 0); STAGE_B2(0, 2, 0);
  STAGE_A(0, 0, 0);  STAGE_A(0, 1, 0);
  STAGE_B2(1, 0, 1); STAGE_B2(1, 2, 1);
  WAITV(4);
  BAR();

#pragma unroll 1
  for (int j = 0; j < NIT; ++j) {
    const int t1 = 2 * j + 1, t2 = 2 * j + 2, t3 = 2 * j + 3;
    // P1: (m01,n01) of tile 2j (buf0); stage A(t1) issue0 -> buf1
    LOADA(0, 0); LOADB(bF0, 0, 0);
    STAGE_A(t1, 0, 1);
    BAR();
    MFMAQ(0, 0, bF0);
    SCHED0(); BAR();
    // P2: (m01,n23); stage A(t1) issue1
    LOADB(bF1, 2, 0);
    STAGE_A(t1, 1, 1);
    BAR();
    MFMAQ(0, 2, bF1);
    SCHED0(); BAR();
    // P3: (m23,n01); stage B(t2) issues 0-1 -> buf0 (B-buf0 reads done @P2)
    LOADA(2, 0);
    STAGE_B2(t2, 0, 0);
    BAR();
    MFMAQ(2, 0, bF0);
    SCHED0(); BAR();
    // P4: (m23,n23); stage B(t2) issues 2-3; counted vmcnt for buf1 tile
    STAGE_B2(t2, 2, 0);
    BAR();
    MFMAQ(2, 2, bF1);
    if (j < NIT - 1) { WAITV(4); } else { WAITV(0); }
    SCHED0(); BAR();
    // P5: tile 2j+1 (buf1) (m01,n01); stage A(t2) issue0 -> buf0 (A-buf0 reads done @P3)
    LOADA(0, 1); LOADB(bF0, 0, 1);
    STAGE_A(t2, 0, 0);
    BAR();
    MFMAQ(0, 0, bF0);
    SCHED0(); BAR();
    // P6: (m01,n23); stage A(t2) issue1
    LOADB(bF1, 2, 1);
    STAGE_A(t2, 1, 0);
    BAR();
    MFMAQ(0, 2, bF1);
    SCHED0(); BAR();
    // P7: (m23,n01); stage B(t3) issues 0-1 -> buf1 (B-buf1 reads done @P6)
    LOADA(2, 1);
    STAGE_B2(t3, 0, 1);
    BAR();
    MFMAQ(2, 0, bF0);
    SCHED0(); BAR();
    // P8: (m23,n23); stage B(t3) issues 2-3; counted vmcnt for next buf0 tile
    STAGE_B2(t3, 2, 1);
    BAR();
    MFMAQ(2, 2, bF1);
    if (j < NIT - 1) { WAITV(4); }
    SCHED0(); BAR();
  }

  // C/D layout (verified m89/m91): col = lane&15, row = (lane>>4)*4 + reg
  const size_t r0 = (size_t)bm * 128 + wm * 64 + (lane >> 4) * 4;
  const int c0 = bn * 256 + wn * 64 + fr;
#pragma unroll
  for (int m = 0; m < 4; ++m)
#pragma unroll
    for (int n = 0; n < 4; ++n)
#pragma unroll
      for (int r = 0; r < 4; ++r)
        C[(r0 + m * 16 + r) * OUT_F + (c0 + n * 16)] = acc[m][n][r];
}

// In-place row LayerNorm with bias add
__global__ __launch_bounds__(256) void ln_kernel(float* __restrict__ C,
                                                 const float* __restrict__ bias,
                                                 const float* __restrict__ gamma,
                                                 const float* __restrict__ beta) {
  const int row = blockIdx.x;
  const int tid = threadIdx.x;
  float4 v = *reinterpret_cast<const float4*>(C + (size_t)row * OUT_F + tid * 4);
  const float4 bb = *reinterpret_cast<const float4*>(bias + tid * 4);
  v.x += bb.x; v.y += bb.y; v.z += bb.z; v.w += bb.w;
  float s = v.x + v.y + v.z + v.w;
  float q = v.x * v.x + v.y * v.y + v.z * v.z + v.w * v.w;
#pragma unroll
  for (int off = 32; off > 0; off >>= 1) {
    s += __shfl_down(s, off);
    q += __shfl_down(q, off);
  }
  __shared__ float red[8];
  const int wave = tid >> 6, lane = tid & 63;
  if (lane == 0) { red[wave] = s; red[4 + wave] = q; }
  __syncthreads();
  s = red[0] + red[1] + red[2] + red[3];
  q = red[4] + red[5] + red[6] + red[7];
  const float mu = s * (1.0f / OUT_F);
  const float var = q * (1.0f / OUT_F) - mu * mu;
  const float rs = rsqrtf(var + LN_EPS);
  const float4 g = *reinterpret_cast<const float4*>(gamma + tid * 4);
  const float4 be = *reinterpret_cast<const float4*>(beta + tid * 4);
  float4 o;
  o.x = g.x * (v.x - mu) * rs + be.x;
  o.y = g.y * (v.y - mu) * rs + be.y;
  o.z = g.z * (v.z - mu) * rs + be.z;
  o.w = g.w * (v.w - mu) * rs + be.w;
  *reinterpret_cast<float4*>(C + (size_t)row * OUT_F + tid * 4) = o;
}

extern "C" void kernel_launch(void* const* d_in, const int* in_sizes, int n_in,
                              void* d_out, int out_size, void* d_ws, size_t ws_size,
                              hipStream_t stream) {
  const float* x     = (const float*)d_in[0];
  const float* cp    = (const float*)d_in[1];
  const float* W     = (const float*)d_in[2];
  const float* bias  = (const float*)d_in[3];
  const float* gamma = (const float*)d_in[4];
  const float* beta  = (const float*)d_in[5];
  float* out = (float*)d_out;

  unsigned short* Bm = (unsigned short*)d_ws;
  const size_t bBytes = (size_t)OUT_F * KP * sizeof(unsigned short);   // 24 MiB
  unsigned short* Af = (unsigned short*)((char*)d_ws + bBytes);
  size_t avail = ws_size > bBytes ? ws_size - bBytes : 0;
  long long fit = (long long)(avail / ((size_t)KP * sizeof(unsigned short)));
  // Prefer chunk sizes whose grid (chunk/128*4) exactly fills 256 CUs.
  int chunk;
  if (fit >= BATCH)      chunk = BATCH;   // 512 WGs = 2 full rounds
  else if (fit >= 8192)  chunk = 8192;    // 256 WGs = 1 full round, x2 chunks
  else if (fit >= 4096)  chunk = 4096;
  else                   chunk = (int)((fit / 256) * 256);
  if (chunk < 256) chunk = 256;

  bgen<<<OUT_F, 256, 0, stream>>>(cp, W, Bm);
  for (int r0 = 0; r0 < BATCH; r0 += chunk) {
    const int rows = (BATCH - r0 < chunk) ? (BATCH - r0) : chunk;
    featgen<<<rows, 256, 0, stream>>>(x, Af, r0);
    const int nbm = rows / 128;
    gemm8p<<<nbm * 4, 512, 0, stream>>>(Af, Bm, out + (size_t)r0 * OUT_F, nbm);
  }
  ln_kernel<<<BATCH, 256, 0, stream>>>(out, bias, gamma, beta);
}

// Round 4
// 458.957 us; speedup vs baseline: 2.5658x; 1.4744x over previous
//
#include <hip/hip_runtime.h>
#include <hip/hip_bf16.h>

#define BATCH   16384
#define IN_F    1024
#define OUT_F   1024
#define KCOLS   11
#define KPL     12          // 11 basis planes + 1 x-plane (for W)
#define KP      (KPL*IN_F)  // 12288
#define KHALF   (KP/2)      // 6144 per split-K block
#define NTKH    (KHALF/64)  // 96 K-tiles of 64 per half
#define NITH    (NTKH/2)    // 48 main-loop iterations (2 K-tiles each)
#define LN_EPS  1e-5f

typedef __attribute__((ext_vector_type(8))) short short8;
typedef __attribute__((ext_vector_type(4))) float f32x4;

static __device__ __forceinline__ unsigned short f2bf(float f) {
  __hip_bfloat16 h = __float2bfloat16(f);
  return *reinterpret_cast<unsigned short*>(&h);
}

// Cox-de Boor, faithful to the reference's in-place variant.
// All denominators are compile-time constants -> multiply by folded reciprocal.
__device__ __forceinline__ void bspline_basis(float x, float bas[KCOLS]) {
  const float s = 1.0f / 11.0f;
  float kn[12];
#pragma unroll
  for (int j = 0; j < 12; ++j) kn[j] = (float)j * s;
  kn[11] = 1.0f;
#pragma unroll
  for (int j = 0; j < 11; ++j)
    bas[j] = (x >= kn[j] && x < kn[j + 1]) ? 1.0f : 0.0f;
#pragma unroll
  for (int d = 1; d <= 3; ++d) {
#pragma unroll
    for (int j = 0; j < 11 - d; ++j) {
      const float r1 = 1.0f / (kn[j + d] - kn[j]);
      const float r2 = 1.0f / (kn[j + d + 1] - kn[j + 1]);
      float a = (x - kn[j]) * r1;
      float c = (kn[j + d + 1] - x) * r2;
      bas[j] = a * bas[j] + c * bas[j + 1];
    }
  }
}

// A[localRow][k*1024 + i] (bf16): 11 basis planes + x plane.
__global__ __launch_bounds__(256) void featgen(const float* __restrict__ X,
                                               unsigned short* __restrict__ A,
                                               int row0) {
  const int brow = blockIdx.x;
  const int i0 = threadIdx.x * 4;
  const float4 xv = *reinterpret_cast<const float4*>(X + (size_t)(row0 + brow) * IN_F + i0);
  float xs[4] = {xv.x, xv.y, xv.z, xv.w};
  float bas[4][KCOLS];
#pragma unroll
  for (int t = 0; t < 4; ++t) bspline_basis(xs[t], bas[t]);
  unsigned short* outp = A + (size_t)brow * KP + i0;
#pragma unroll
  for (int k = 0; k < KCOLS; ++k) {
    ushort4 u;
    u.x = f2bf(bas[0][k]); u.y = f2bf(bas[1][k]);
    u.z = f2bf(bas[2][k]); u.w = f2bf(bas[3][k]);
    *reinterpret_cast<ushort4*>(outp + (size_t)k * IN_F) = u;
  }
  ushort4 u;
  u.x = f2bf(xs[0]); u.y = f2bf(xs[1]); u.z = f2bf(xs[2]); u.w = f2bf(xs[3]);
  *reinterpret_cast<ushort4*>(outp + (size_t)KCOLS * IN_F) = u;
}

// Bmat[o][k*1024 + i] (bf16): cp planes + W plane.
__global__ __launch_bounds__(256) void bgen(const float* __restrict__ CP,
                                            const float* __restrict__ W,
                                            unsigned short* __restrict__ Bm) {
  const int o = blockIdx.x;
  const int i0 = threadIdx.x * 4;
  unsigned short* outp = Bm + (size_t)o * KP + i0;
#pragma unroll
  for (int k = 0; k < KCOLS; ++k) {
    ushort4 u;
    u.x = f2bf(CP[((size_t)o * IN_F + i0 + 0) * KCOLS + k]);
    u.y = f2bf(CP[((size_t)o * IN_F + i0 + 1) * KCOLS + k]);
    u.z = f2bf(CP[((size_t)o * IN_F + i0 + 2) * KCOLS + k]);
    u.w = f2bf(CP[((size_t)o * IN_F + i0 + 3) * KCOLS + k]);
    *reinterpret_cast<ushort4*>(outp + (size_t)k * IN_F) = u;
  }
  ushort4 u;
  u.x = f2bf(W[(size_t)o * IN_F + i0 + 0]);
  u.y = f2bf(W[(size_t)o * IN_F + i0 + 1]);
  u.z = f2bf(W[(size_t)o * IN_F + i0 + 2]);
  u.w = f2bf(W[(size_t)o * IN_F + i0 + 3]);
  *reinterpret_cast<ushort4*>(outp + (size_t)KCOLS * IN_F) = u;
}

// ---------------- 256x256 8-phase split-K GEMM ----------------
// ks=0 blocks: C0 = A[:, 0:6144)    * B^T half  -> plain store to Cc
// ks=1 blocks: C1 = A[:, 6144:12288)* B^T half  -> plain store to Cp
// Grid = nbm * 4(bn) * 2(ks); at 8192 rows -> 256 WGs = exact full CU fill.
// 512 thr = 8 waves (2M x 4N); BK=64; LDS 128 KiB double-buffered.

#define BAR()    __builtin_amdgcn_s_barrier()
#define SCHED0() __builtin_amdgcn_sched_barrier(0)
#define WAITV(N) asm volatile("s_waitcnt vmcnt(" #N ")" ::: "memory")

__global__ __launch_bounds__(512, 2) void gemm8p(const unsigned short* __restrict__ A,
                                                 const unsigned short* __restrict__ Bm,
                                                 float* __restrict__ Cc,
                                                 float* __restrict__ Cp, int nbm) {
  __shared__ unsigned short lds[2][2][2][128 * 64];  // [buf][A=0/B=1][half][...]
  const int tid  = (int)threadIdx.x;
  const int lane = tid & 63;
  const int w    = tid >> 6;
  const int wm   = w >> 2;       // 0..1
  const int wn   = w & 3;        // 0..3

  // XCD-aware bijective swizzle; per-XCD chunk = {4 bm} x {2 ks} x {4 bn}.
  const int nwg = nbm * 8;
  const int cpx = nwg >> 3;
  const int bid = (int)blockIdx.x;
  const int swz = (bid & 7) * cpx + (bid >> 3);
  const int bn = swz & 3;
  const int ks = (swz >> 2) & 1;
  const int bm = swz >> 3;
  const size_t koff = (size_t)ks * KHALF;
  float* __restrict__ C = ks ? Cp : Cc;

  // staging: one issue = 512 thr x 16 B = 64 rows x 64 cols.
  // Linear LDS dest; source col carries the inverse swizzle c ^ (row&7).
  const int srow = (w << 3) + (lane >> 3);            // 0..63 within one issue
  const int scol = ((lane & 7) ^ (lane >> 3)) << 3;   // element col, swizzled
  const unsigned short* aB = A  + (size_t)(bm * 256 + srow) * KP + koff + scol;
  const unsigned short* bB = Bm + (size_t)(bn * 256 + srow) * KP + koff + scol;

#define STAGE(T, AB, H, BUF)                                                          \
  do {                                                                                \
    if ((T) < NTKH) {                                                                 \
      const unsigned short* g_ = ((AB) ? bB : aB) + (size_t)(H) * 128 * KP + (size_t)(T) * 64; \
      unsigned short* l_ = &lds[BUF][AB][H][w * 512];                                 \
      __builtin_amdgcn_global_load_lds((const __attribute__((address_space(1))) void*)g_,       \
                                       (__attribute__((address_space(3))) void*)l_, 16, 0, 0);  \
      __builtin_amdgcn_global_load_lds((const __attribute__((address_space(1))) void*)(g_ + (size_t)64 * KP), \
                                       (__attribute__((address_space(3))) void*)(l_ + 4096), 16, 0, 0); \
    }                                                                                 \
  } while (0)

  // fragment reads (ds_read_b128, swizzled col)
  const int fr = lane & 15;
  const int g4 = lane >> 4;
  const int s7 = lane & 7;
  const int col0 = ((g4 ^ s7) << 3);        // kk=0 (elements)
  const int col1 = (((4 + g4) ^ s7) << 3);  // kk=1
  const unsigned short* aH[2] = {&lds[0][0][wm][0], &lds[1][0][wm][0]};
  const unsigned short* bH[2] = {&lds[0][1][wn >> 1][0], &lds[1][1][wn >> 1][0]};
  const int brow0 = (wn & 1) * 64;

  short8 aF[4][2], bF0[2][2], bF1[2][2];
  f32x4 acc[8][4] = {};

#define LOADA(MB, BUF)                                                         \
  do {                                                                         \
    _Pragma("unroll") for (int m_ = 0; m_ < 4; ++m_) {                         \
      const unsigned short* p_ = aH[BUF] + ((MB) + m_) * 1024 + fr * 64;       \
      aF[m_][0] = *reinterpret_cast<const short8*>(p_ + col0);                 \
      aF[m_][1] = *reinterpret_cast<const short8*>(p_ + col1);                 \
    }                                                                          \
  } while (0)

#define LOADB(DST, NB, BUF)                                                    \
  do {                                                                         \
    _Pragma("unroll") for (int n_ = 0; n_ < 2; ++n_) {                         \
      const unsigned short* p_ = bH[BUF] + (brow0 + ((NB) + n_) * 16 + fr) * 64; \
      DST[n_][0] = *reinterpret_cast<const short8*>(p_ + col0);                \
      DST[n_][1] = *reinterpret_cast<const short8*>(p_ + col1);                \
    }                                                                          \
  } while (0)

#define MFMAQ(MB, NB, BF)                                                      \
  do {                                                                         \
    __builtin_amdgcn_s_setprio(1);                                             \
    _Pragma("unroll") for (int m_ = 0; m_ < 4; ++m_)                           \
    _Pragma("unroll") for (int n_ = 0; n_ < 2; ++n_)                           \
    _Pragma("unroll") for (int kk_ = 0; kk_ < 2; ++kk_)                        \
      acc[(MB) + m_][(NB) + n_] = __builtin_amdgcn_mfma_f32_16x16x32_bf16(     \
          aF[m_][kk_], BF[n_][kk_], acc[(MB) + m_][(NB) + n_], 0, 0, 0);       \
    __builtin_amdgcn_s_setprio(0);                                             \
  } while (0)

  // prologue: tile0 (B0,B1,A0,A1) + tile1 (B0,B1); drain to 4 outstanding.
  STAGE(0, 1, 0, 0); STAGE(0, 1, 1, 0);
  STAGE(0, 0, 0, 0); STAGE(0, 0, 1, 0);
  STAGE(1, 1, 0, 1); STAGE(1, 1, 1, 1);
  WAITV(4);
  BAR();

#pragma unroll 1
  for (int j = 0; j < NITH; ++j) {
    const int tA = 2 * j + 1, tB2 = 2 * j + 2, tB3 = 2 * j + 3;
    // P1: quad(m0-3,n0-1) of tile 2j (buf0); stage A-half0 of tile 2j+1 -> buf1
    LOADA(0, 0); LOADB(bF0, 0, 0);
    STAGE(tA, 0, 0, 1);
    BAR();
    MFMAQ(0, 0, bF0);
    SCHED0(); BAR();
    // P2: quad(m0-3,n2-3); stage A-half1 of 2j+1
    LOADB(bF1, 2, 0);
    STAGE(tA, 0, 1, 1);
    BAR();
    MFMAQ(0, 2, bF1);
    SCHED0(); BAR();
    // P3: quad(m4-7,n0-1); stage B-half0 of 2j+2 -> buf0 (B reads of buf0 done @P2)
    LOADA(4, 0);
    STAGE(tB2, 1, 0, 0);
    BAR();
    MFMAQ(4, 0, bF0);
    SCHED0(); BAR();
    // P4: quad(m4-7,n2-3); stage B-half1 of 2j+2; counted vmcnt for buf1 tile
    STAGE(tB2, 1, 1, 0);
    BAR();
    MFMAQ(4, 2, bF1);
    if (j < NITH - 1) { WAITV(4); } else { WAITV(0); }
    SCHED0(); BAR();
    // P5: tile 2j+1 (buf1) quad(m0-3,n0-1); stage A-half0 of 2j+2 (A reads of buf0 done @P3)
    LOADA(0, 1); LOADB(bF0, 0, 1);
    STAGE(tB2, 0, 0, 0);
    BAR();
    MFMAQ(0, 0, bF0);
    SCHED0(); BAR();
    // P6: quad(m0-3,n2-3); stage A-half1 of 2j+2
    LOADB(bF1, 2, 1);
    STAGE(tB2, 0, 1, 0);
    BAR();
    MFMAQ(0, 2, bF1);
    SCHED0(); BAR();
    // P7: quad(m4-7,n0-1); stage B-half0 of 2j+3 -> buf1 (B reads of buf1 done @P6)
    LOADA(4, 1);
    STAGE(tB3, 1, 0, 1);
    BAR();
    MFMAQ(4, 0, bF0);
    SCHED0(); BAR();
    // P8: quad(m4-7,n2-3); stage B-half1 of 2j+3; counted vmcnt for next buf0 tile
    STAGE(tB3, 1, 1, 1);
    BAR();
    MFMAQ(4, 2, bF1);
    if (j < NITH - 1) { WAITV(4); }
    SCHED0(); BAR();
  }

  // C/D layout (verified m89/m91): col = lane&15, row = (lane>>4)*4 + reg
  const size_t r0 = (size_t)bm * 256 + wm * 128 + (lane >> 4) * 4;
  const int c0 = bn * 256 + wn * 64 + fr;
#pragma unroll
  for (int m = 0; m < 8; ++m)
#pragma unroll
    for (int n = 0; n < 4; ++n)
#pragma unroll
      for (int r = 0; r < 4; ++r)
        C[(r0 + m * 16 + r) * OUT_F + (c0 + n * 16)] = acc[m][n][r];
}

// Row LayerNorm over C0+C1+bias, written in place to C0.
__global__ __launch_bounds__(256) void ln_kernel(float* __restrict__ C,
                                                 const float* __restrict__ P,
                                                 const float* __restrict__ bias,
                                                 const float* __restrict__ gamma,
                                                 const float* __restrict__ beta) {
  const int row = blockIdx.x;
  const int tid = threadIdx.x;
  float4 v = *reinterpret_cast<const float4*>(C + (size_t)row * OUT_F + tid * 4);
  const float4 p = *reinterpret_cast<const float4*>(P + (size_t)row * OUT_F + tid * 4);
  const float4 bb = *reinterpret_cast<const float4*>(bias + tid * 4);
  v.x += p.x + bb.x; v.y += p.y + bb.y; v.z += p.z + bb.z; v.w += p.w + bb.w;
  float s = v.x + v.y + v.z + v.w;
  float q = v.x * v.x + v.y * v.y + v.z * v.z + v.w * v.w;
#pragma unroll
  for (int off = 32; off > 0; off >>= 1) {
    s += __shfl_down(s, off);
    q += __shfl_down(q, off);
  }
  __shared__ float red[8];
  const int wave = tid >> 6, lane = tid & 63;
  if (lane == 0) { red[wave] = s; red[4 + wave] = q; }
  __syncthreads();
  s = red[0] + red[1] + red[2] + red[3];
  q = red[4] + red[5] + red[6] + red[7];
  const float mu = s * (1.0f / OUT_F);
  const float var = q * (1.0f / OUT_F) - mu * mu;
  const float rs = rsqrtf(var + LN_EPS);
  const float4 g = *reinterpret_cast<const float4*>(gamma + tid * 4);
  const float4 be = *reinterpret_cast<const float4*>(beta + tid * 4);
  float4 o;
  o.x = g.x * (v.x - mu) * rs + be.x;
  o.y = g.y * (v.y - mu) * rs + be.y;
  o.z = g.z * (v.z - mu) * rs + be.z;
  o.w = g.w * (v.w - mu) * rs + be.w;
  *reinterpret_cast<float4*>(C + (size_t)row * OUT_F + tid * 4) = o;
}

extern "C" void kernel_launch(void* const* d_in, const int* in_sizes, int n_in,
                              void* d_out, int out_size, void* d_ws, size_t ws_size,
                              hipStream_t stream) {
  const float* x     = (const float*)d_in[0];
  const float* cp    = (const float*)d_in[1];
  const float* W     = (const float*)d_in[2];
  const float* bias  = (const float*)d_in[3];
  const float* gamma = (const float*)d_in[4];
  const float* beta  = (const float*)d_in[5];
  float* out = (float*)d_out;

  unsigned short* Bm = (unsigned short*)d_ws;
  const size_t bBytes = (size_t)OUT_F * KP * sizeof(unsigned short);   // 24 MiB
  size_t avail = ws_size > bBytes ? ws_size - bBytes : 0;
  // per-row: 24 KiB bf16 features + 4 KiB fp32 partial
  const size_t perRow = (size_t)KP * 2 + (size_t)OUT_F * 4;
  long long fit = (long long)(avail / perRow);
  int chunk;
  if (fit >= BATCH)     chunk = BATCH;   // 512 WGs = 2 full fill rounds
  else if (fit >= 8192) chunk = 8192;    // 256 WGs = exact full fill
  else                  chunk = (int)((fit / 256) * 256);
  if (chunk < 256) chunk = 256;

  unsigned short* Af = (unsigned short*)((char*)d_ws + bBytes);
  float* P = (float*)(Af + (size_t)chunk * KP);

  bgen<<<OUT_F, 256, 0, stream>>>(cp, W, Bm);
  for (int r0 = 0; r0 < BATCH; r0 += chunk) {
    const int rows = (BATCH - r0 < chunk) ? (BATCH - r0) : chunk;
    featgen<<<rows, 256, 0, stream>>>(x, Af, r0);
    const int nbm = rows / 256;
    gemm8p<<<nbm * 8, 512, 0, stream>>>(Af, Bm, out + (size_t)r0 * OUT_F, P, nbm);
    ln_kernel<<<rows, 256, 0, stream>>>(out + (size_t)r0 * OUT_F, P, bias, gamma, beta);
  }
}